// Round 1
// baseline (596.079 us; speedup 1.0000x reference)
//
#include <hip/hip_runtime.h>

#define N_NODES 50000
#define N_EDGES 400000
#define E_TOT   (N_EDGES + N_NODES)   // 450000, self-loops appended
#define IN_C 128
#define HID  512
#define OUT2 64
#define NEG_SLOPE 0.2f

__device__ __forceinline__ float wave_sum(float v) {
#pragma unroll
  for (int o = 32; o > 0; o >>= 1) v += __shfl_xor(v, o, 64);
  return v;
}
__device__ __forceinline__ float wave_max(float v) {
#pragma unroll
  for (int o = 32; o > 0; o >>= 1) v = fmaxf(v, __shfl_xor(v, o, 64));
  return v;
}

// src node of logical edge e (e >= N_EDGES are self-loops)
__device__ __forceinline__ int esrc(const int* __restrict__ ei, int e) {
  return (e < N_EDGES) ? ei[e] : (e - N_EDGES);
}
__device__ __forceinline__ int edst(const int* __restrict__ ei, int e) {
  return (e < N_EDGES) ? ei[N_EDGES + e] : (e - N_EDGES);
}

// ---- CSR build -------------------------------------------------------------
__global__ void count_deg(const int* __restrict__ ei, int* __restrict__ deg) {
  int e = blockIdx.x * blockDim.x + threadIdx.x;
  if (e >= E_TOT) return;
  atomicAdd(&deg[edst(ei, e)], 1);
}

// single-block hierarchical scan: deg[N] -> row_ptr[N+1] (exclusive, rp[0]=0)
__global__ void scan_deg(const int* __restrict__ deg, int* __restrict__ row_ptr) {
  __shared__ int wsum[16];
  __shared__ int s_carry;
  int t = threadIdx.x, lane = t & 63, w = t >> 6;
  if (t == 0) { s_carry = 0; row_ptr[0] = 0; }
  __syncthreads();
  for (int base = 0; base < N_NODES; base += 1024) {
    int i = base + t;
    int v = (i < N_NODES) ? deg[i] : 0;
    int sc = v;
#pragma unroll
    for (int off = 1; off < 64; off <<= 1) {
      int u = __shfl_up(sc, off, 64);
      if (lane >= off) sc += u;
    }
    if (lane == 63) wsum[w] = sc;
    __syncthreads();
    if (w == 0 && lane < 16) {
      int ws = wsum[lane];
#pragma unroll
      for (int off = 1; off < 16; off <<= 1) {
        int u = __shfl_up(ws, off, 64);
        if (lane >= off) ws += u;
      }
      wsum[lane] = ws;
    }
    __syncthreads();
    int carry = s_carry;
    int excl_wave = (w == 0) ? 0 : wsum[w - 1];
    int incl = sc + excl_wave + carry;
    if (i < N_NODES) row_ptr[i + 1] = incl;
    __syncthreads();
    if (t == 1023) s_carry = incl;
    __syncthreads();
  }
}

__global__ void fill_csr(const int* __restrict__ ei, const int* __restrict__ row_ptr,
                         int* __restrict__ cursor, int* __restrict__ csr_e) {
  int e = blockIdx.x * blockDim.x + threadIdx.x;
  if (e >= E_TOT) return;
  int d = edst(ei, e);
  int pos = atomicAdd(&cursor[d], 1);
  csr_e[row_ptr[d] + pos] = e;
}

// ---- layer-1 score vectors: w1s = W1 @ a1_src, w1d = W1 @ a1_dst ----------
__global__ void matvec_w1(const float* __restrict__ W1, const float* __restrict__ a1s,
                          const float* __restrict__ a1d, float* __restrict__ w1s,
                          float* __restrict__ w1d) {
  int c = threadIdx.x;  // 128 threads
  if (c >= IN_C) return;
  const float* row = W1 + (size_t)c * HID;
  float s = 0.f, d = 0.f;
  for (int j = 0; j < HID; j++) { float w = row[j]; s += w * a1s[j]; d += w * a1d[j]; }
  w1s[c] = s; w1d[c] = d;
}

// alpha_s[i] = x[i] . w1s ; alpha_d[i] = x[i] . w1d  (one wave per node)
__global__ void node_scores128(const float* __restrict__ x, const float* __restrict__ ws,
                               const float* __restrict__ wd, float* __restrict__ as_,
                               float* __restrict__ ad_) {
  int wid = (blockIdx.x * blockDim.x + threadIdx.x) >> 6;
  int lane = threadIdx.x & 63;
  if (wid >= N_NODES) return;
  const float* row = x + (size_t)wid * IN_C;
  float s = row[lane] * ws[lane] + row[lane + 64] * ws[lane + 64];
  float d = row[lane] * wd[lane] + row[lane + 64] * wd[lane + 64];
  s = wave_sum(s); d = wave_sum(d);
  if (lane == 0) { as_[wid] = s; ad_[wid] = d; }
}

// layer-2 scores from h2 directly (64 channels = 64 lanes)
__global__ void node_scores64(const float* __restrict__ h2, const float* __restrict__ a2s,
                              const float* __restrict__ a2d, float* __restrict__ as_,
                              float* __restrict__ ad_) {
  int wid = (blockIdx.x * blockDim.x + threadIdx.x) >> 6;
  int lane = threadIdx.x & 63;
  if (wid >= N_NODES) return;
  float v = h2[(size_t)wid * OUT2 + lane];
  float s = wave_sum(v * a2s[lane]);
  float d = wave_sum(v * a2d[lane]);
  if (lane == 0) { as_[wid] = s; ad_[wid] = d; }
}

// segment softmax over incoming edges of each dst node (one wave per node)
__global__ void seg_softmax(const int* __restrict__ ei, const int* __restrict__ row_ptr,
                            const int* __restrict__ csr_e, const float* __restrict__ as_,
                            const float* __restrict__ ad_, float* __restrict__ alpha) {
  int wid = (blockIdx.x * blockDim.x + threadIdx.x) >> 6;
  int lane = threadIdx.x & 63;
  if (wid >= N_NODES) return;
  int beg = row_ptr[wid], end = row_ptr[wid + 1];
  float adv = ad_[wid];
  float m = -3.4e38f;
  for (int k = beg + lane; k < end; k += 64) {
    int e = csr_e[k];
    float t = as_[esrc(ei, e)] + adv;
    t = (t > 0.f) ? t : NEG_SLOPE * t;
    m = fmaxf(m, t);
  }
  m = wave_max(m);
  float sum = 0.f;
  for (int k = beg + lane; k < end; k += 64) {
    int e = csr_e[k];
    float t = as_[esrc(ei, e)] + adv;
    t = (t > 0.f) ? t : NEG_SLOPE * t;
    float ex = __expf(t - m);
    alpha[k] = ex;           // indexed by CSR position
    sum += ex;
  }
  sum = wave_sum(sum);
  float inv = 1.f / sum;
  for (int k = beg + lane; k < end; k += 64) alpha[k] *= inv;
}

// xa[dst] = sum_e alpha_e * x[src]  (input-space aggregation, 128 ch, wave/node)
__global__ void aggregate128(const int* __restrict__ ei, const int* __restrict__ row_ptr,
                             const int* __restrict__ csr_e, const float* __restrict__ alpha,
                             const float* __restrict__ x, float* __restrict__ xa) {
  int wid = (blockIdx.x * blockDim.x + threadIdx.x) >> 6;
  int lane = threadIdx.x & 63;
  if (wid >= N_NODES) return;
  int beg = row_ptr[wid], end = row_ptr[wid + 1];
  float a0 = 0.f, a1 = 0.f;
  for (int k = beg; k < end; k++) {
    int e = csr_e[k];
    int s = esrc(ei, e);
    float w = alpha[k];
    const float* row = x + (size_t)s * IN_C;
    a0 += w * row[lane];
    a1 += w * row[lane + 64];
  }
  xa[(size_t)wid * IN_C + lane] = a0;
  xa[(size_t)wid * IN_C + 64 + lane] = a1;
}

// out1 = relu(xa @ W1 + b1)   [N,128]x[128,512]; 64x64 tile, 4x4 per thread
__launch_bounds__(256)
__global__ void gemm1_relu(const float* __restrict__ xa, const float* __restrict__ W1,
                           const float* __restrict__ b1, float* __restrict__ out1) {
  __shared__ float xs[64][132];  // pad -> 2-way LDS conflict max (free)
  int m0 = blockIdx.x * 64;
  int n0 = blockIdx.y * 64;
  int t = threadIdx.x;
#pragma unroll
  for (int j = 0; j < 8; j++) {
    int idx = t + j * 256;          // 2048 float4 slots
    int row = idx >> 5, c4 = idx & 31;
    int gr = m0 + row;
    float4 v = make_float4(0.f, 0.f, 0.f, 0.f);
    if (gr < N_NODES) v = *(const float4*)(xa + (size_t)gr * IN_C + c4 * 4);
    *(float4*)&xs[row][c4 * 4] = v;
  }
  __syncthreads();
  int tr = t >> 4, tc = t & 15;
  float acc[4][4] = {};
  const float* wp = W1 + n0 + tc * 4;
  for (int k = 0; k < IN_C; k++) {
    float a0 = xs[tr * 4 + 0][k], a1 = xs[tr * 4 + 1][k];
    float a2 = xs[tr * 4 + 2][k], a3 = xs[tr * 4 + 3][k];
    float4 b = *(const float4*)(wp + (size_t)k * HID);
    acc[0][0] += a0 * b.x; acc[0][1] += a0 * b.y; acc[0][2] += a0 * b.z; acc[0][3] += a0 * b.w;
    acc[1][0] += a1 * b.x; acc[1][1] += a1 * b.y; acc[1][2] += a1 * b.z; acc[1][3] += a1 * b.w;
    acc[2][0] += a2 * b.x; acc[2][1] += a2 * b.y; acc[2][2] += a2 * b.z; acc[2][3] += a2 * b.w;
    acc[3][0] += a3 * b.x; acc[3][1] += a3 * b.y; acc[3][2] += a3 * b.z; acc[3][3] += a3 * b.w;
  }
  float4 bias = *(const float4*)(b1 + n0 + tc * 4);
#pragma unroll
  for (int j = 0; j < 4; j++) {
    int gr = m0 + tr * 4 + j;
    if (gr < N_NODES) {
      float4 o;
      o.x = fmaxf(acc[j][0] + bias.x, 0.f);
      o.y = fmaxf(acc[j][1] + bias.y, 0.f);
      o.z = fmaxf(acc[j][2] + bias.z, 0.f);
      o.w = fmaxf(acc[j][3] + bias.w, 0.f);
      *(float4*)(out1 + (size_t)gr * HID + n0 + tc * 4) = o;
    }
  }
}

// h2 = out1 @ W2   [N,512]x[512,64]; 64-row tile, full 64-col width, 4x4/thread
__launch_bounds__(256)
__global__ void gemm2(const float* __restrict__ h_in, const float* __restrict__ W2,
                      float* __restrict__ h2) {
  __shared__ float hs[64][68];
  int m0 = blockIdx.x * 64;
  int t = threadIdx.x;
  int tr = t >> 4, tc = t & 15;
  float acc[4][4] = {};
  for (int kb = 0; kb < HID; kb += 64) {
#pragma unroll
    for (int j = 0; j < 4; j++) {
      int idx = t + j * 256;          // 1024 float4 slots
      int row = idx >> 4, c4 = idx & 15;
      int gr = m0 + row;
      float4 v = make_float4(0.f, 0.f, 0.f, 0.f);
      if (gr < N_NODES) v = *(const float4*)(h_in + (size_t)gr * HID + kb + c4 * 4);
      *(float4*)&hs[row][c4 * 4] = v;
    }
    __syncthreads();
    for (int k = 0; k < 64; k++) {
      float a0 = hs[tr * 4 + 0][k], a1 = hs[tr * 4 + 1][k];
      float a2 = hs[tr * 4 + 2][k], a3 = hs[tr * 4 + 3][k];
      float4 b = *(const float4*)(W2 + (size_t)(kb + k) * OUT2 + tc * 4);
      acc[0][0] += a0 * b.x; acc[0][1] += a0 * b.y; acc[0][2] += a0 * b.z; acc[0][3] += a0 * b.w;
      acc[1][0] += a1 * b.x; acc[1][1] += a1 * b.y; acc[1][2] += a1 * b.z; acc[1][3] += a1 * b.w;
      acc[2][0] += a2 * b.x; acc[2][1] += a2 * b.y; acc[2][2] += a2 * b.z; acc[2][3] += a2 * b.w;
      acc[3][0] += a3 * b.x; acc[3][1] += a3 * b.y; acc[3][2] += a3 * b.z; acc[3][3] += a3 * b.w;
    }
    __syncthreads();
  }
#pragma unroll
  for (int j = 0; j < 4; j++) {
    int gr = m0 + tr * 4 + j;
    if (gr < N_NODES) {
      float4 o = make_float4(acc[j][0], acc[j][1], acc[j][2], acc[j][3]);
      *(float4*)(h2 + (size_t)gr * OUT2 + tc * 4) = o;
    }
  }
}

// out[dst] = (relu(sum_e alpha_e*h2[src] + b2)) @ fcW + fcb   (wave per node)
__global__ void agg2_final(const int* __restrict__ ei, const int* __restrict__ row_ptr,
                           const int* __restrict__ csr_e, const float* __restrict__ alpha,
                           const float* __restrict__ h2, const float* __restrict__ b2,
                           const float* __restrict__ fcW, const float* __restrict__ fcb,
                           float* __restrict__ out) {
  int wid = (blockIdx.x * blockDim.x + threadIdx.x) >> 6;
  int lane = threadIdx.x & 63;
  if (wid >= N_NODES) return;
  int beg = row_ptr[wid], end = row_ptr[wid + 1];
  float acc = 0.f;
  for (int k = beg; k < end; k++) {
    int e = csr_e[k];
    int s = esrc(ei, e);
    acc += alpha[k] * h2[(size_t)s * OUT2 + lane];
  }
  float v = fmaxf(acc + b2[lane], 0.f);
  float f0 = wave_sum(v * fcW[lane * 2 + 0]);
  float f1 = wave_sum(v * fcW[lane * 2 + 1]);
  if (lane == 0) {
    out[(size_t)wid * 2 + 0] = f0 + fcb[0];
    out[(size_t)wid * 2 + 1] = f1 + fcb[1];
  }
}

extern "C" void kernel_launch(void* const* d_in, const int* in_sizes, int n_in,
                              void* d_out, int out_size, void* d_ws, size_t ws_size,
                              hipStream_t stream) {
  const float* x    = (const float*)d_in[0];
  const int*   ei   = (const int*)d_in[1];
  const float* W1   = (const float*)d_in[2];
  const float* a1s  = (const float*)d_in[3];
  const float* a1d  = (const float*)d_in[4];
  const float* b1   = (const float*)d_in[5];
  const float* W2   = (const float*)d_in[6];
  const float* a2s  = (const float*)d_in[7];
  const float* a2d  = (const float*)d_in[8];
  const float* b2   = (const float*)d_in[9];
  const float* fcW  = (const float*)d_in[10];
  const float* fcb  = (const float*)d_in[11];
  float* out = (float*)d_out;

  char* p = (char*)d_ws;
  float* xa    = (float*)p; p += (size_t)N_NODES * IN_C * 4;
  float* out1  = (float*)p; p += (size_t)N_NODES * HID * 4;
  float* h2    = (float*)p; p += (size_t)N_NODES * OUT2 * 4;
  float* as1   = (float*)p; p += (size_t)N_NODES * 4;
  float* ad1   = (float*)p; p += (size_t)N_NODES * 4;
  float* alpha = (float*)p; p += (size_t)E_TOT * 4;
  float* w1s   = (float*)p; p += 128 * 4;
  float* w1d   = (float*)p; p += 128 * 4;
  int* row_ptr = (int*)p;   p += (size_t)(N_NODES + 1) * 4;
  int* deg     = (int*)p;   p += (size_t)N_NODES * 4;   // also reused as cursor
  int* csr_e   = (int*)p;   p += (size_t)E_TOT * 4;

  const int edge_blocks = (E_TOT + 255) / 256;
  const int node_wave_blocks = (N_NODES + 3) / 4;   // 4 waves per 256-thread block
  const int m_tiles = (N_NODES + 63) / 64;

  // ---- CSR build (shared by both layers) ----
  hipMemsetAsync(deg, 0, (size_t)N_NODES * 4, stream);
  count_deg<<<edge_blocks, 256, 0, stream>>>(ei, deg);
  scan_deg<<<1, 1024, 0, stream>>>(deg, row_ptr);
  hipMemsetAsync(deg, 0, (size_t)N_NODES * 4, stream);
  fill_csr<<<edge_blocks, 256, 0, stream>>>(ei, row_ptr, deg, csr_e);

  // ---- layer 1 (aggregate in input space, then GEMM) ----
  matvec_w1<<<1, 128, 0, stream>>>(W1, a1s, a1d, w1s, w1d);
  node_scores128<<<node_wave_blocks, 256, 0, stream>>>(x, w1s, w1d, as1, ad1);
  seg_softmax<<<node_wave_blocks, 256, 0, stream>>>(ei, row_ptr, csr_e, as1, ad1, alpha);
  aggregate128<<<node_wave_blocks, 256, 0, stream>>>(ei, row_ptr, csr_e, alpha, x, xa);
  gemm1_relu<<<dim3(m_tiles, HID / 64), 256, 0, stream>>>(xa, W1, b1, out1);

  // ---- layer 2 (standard orientation: GEMM, scores, aggregate in 64-ch) ----
  gemm2<<<m_tiles, 256, 0, stream>>>(out1, W2, h2);
  node_scores64<<<node_wave_blocks, 256, 0, stream>>>(h2, a2s, a2d, as1, ad1);
  seg_softmax<<<node_wave_blocks, 256, 0, stream>>>(ei, row_ptr, csr_e, as1, ad1, alpha);
  agg2_final<<<node_wave_blocks, 256, 0, stream>>>(ei, row_ptr, csr_e, alpha, h2, b2, fcW, fcb, out);
}

// Round 4
// 421.390 us; speedup vs baseline: 1.4146x; 1.4146x over previous
//
#include <hip/hip_runtime.h>

#define N_NODES 50000
#define N_EDGES 400000
#define E_TOT   (N_EDGES + N_NODES)   // 450000, self-loops appended
#define IN_C 128
#define HID  512
#define OUT2 64
#define NEG_SLOPE 0.2f

__device__ __forceinline__ float wave_sum(float v) {
#pragma unroll
  for (int o = 32; o > 0; o >>= 1) v += __shfl_xor(v, o, 64);
  return v;
}
__device__ __forceinline__ int wave_sum_i(int v) {
#pragma unroll
  for (int o = 32; o > 0; o >>= 1) v += __shfl_xor(v, o, 64);
  return v;
}
__device__ __forceinline__ float wave_max(float v) {
#pragma unroll
  for (int o = 32; o > 0; o >>= 1) v = fmaxf(v, __shfl_xor(v, o, 64));
  return v;
}
__device__ __forceinline__ float leaky(float t) {
  return (t > 0.f) ? t : NEG_SLOPE * t;
}

// src/dst of logical edge e (e >= N_EDGES are self-loops)
__device__ __forceinline__ int esrc(const int* __restrict__ ei, int e) {
  return (e < N_EDGES) ? ei[e] : (e - N_EDGES);
}
__device__ __forceinline__ int edst(const int* __restrict__ ei, int e) {
  return (e < N_EDGES) ? ei[N_EDGES + e] : (e - N_EDGES);
}

// ---- CSR build -------------------------------------------------------------
__global__ void count_deg(const int* __restrict__ ei, int* __restrict__ deg) {
  int e = blockIdx.x * blockDim.x + threadIdx.x;
  if (e >= E_TOT) return;
  atomicAdd(&deg[edst(ei, e)], 1);
}

// 3-phase scan: A) per-block sums  B) scan block sums  C) in-block scan + offset
__global__ void scanA(const int* __restrict__ deg, int* __restrict__ bsum) {
  __shared__ int ws[16];
  int t = threadIdx.x, lane = t & 63, w = t >> 6;
  int i = blockIdx.x * 1024 + t;
  int v = (i < N_NODES) ? deg[i] : 0;
  int s = wave_sum_i(v);
  if (lane == 0) ws[w] = s;
  __syncthreads();
  if (t == 0) {
    int tot = 0;
#pragma unroll
    for (int k = 0; k < 16; k++) tot += ws[k];
    bsum[blockIdx.x] = tot;
  }
}

__global__ void scanB(const int* __restrict__ bsum, int* __restrict__ boff, int nb) {
  int lane = threadIdx.x;  // 64 threads
  int v = (lane < nb) ? bsum[lane] : 0;
  int sc = v;
#pragma unroll
  for (int off = 1; off < 64; off <<= 1) {
    int u = __shfl_up(sc, off, 64);
    if (lane >= off) sc += u;
  }
  if (lane < nb) boff[lane] = sc - v;  // exclusive
}

__global__ void scanC(const int* __restrict__ deg, const int* __restrict__ boff,
                      int* __restrict__ row_ptr) {
  __shared__ int ws[16];
  int t = threadIdx.x, lane = t & 63, w = t >> 6;
  int i = blockIdx.x * 1024 + t;
  int v = (i < N_NODES) ? deg[i] : 0;
  int sc = v;
#pragma unroll
  for (int off = 1; off < 64; off <<= 1) {
    int u = __shfl_up(sc, off, 64);
    if (lane >= off) sc += u;
  }
  if (lane == 63) ws[w] = sc;
  __syncthreads();
  if (w == 0 && lane < 16) {
    int u = ws[lane];
#pragma unroll
    for (int off = 1; off < 16; off <<= 1) {
      int uu = __shfl_up(u, off, 64);
      if (lane >= off) u += uu;
    }
    ws[lane] = u;
  }
  __syncthreads();
  int excl = ((w > 0) ? ws[w - 1] : 0) + boff[blockIdx.x];
  if (i < N_NODES) row_ptr[i + 1] = sc + excl;
  if (blockIdx.x == 0 && t == 0) row_ptr[0] = 0;
}

// store SRC id directly (drops the ei indirection from all later gathers)
__global__ void fill_csr(const int* __restrict__ ei, const int* __restrict__ row_ptr,
                         int* __restrict__ cursor, int* __restrict__ csr_src) {
  int e = blockIdx.x * blockDim.x + threadIdx.x;
  if (e >= E_TOT) return;
  int d = edst(ei, e);
  int pos = atomicAdd(&cursor[d], 1);
  csr_src[row_ptr[d] + pos] = esrc(ei, e);
}

// ---- layer-1 score vectors: w1s = W1 @ a1_src, w1d = W1 @ a1_dst ----------
// one wave per channel; coalesced row reads + wave reduce
__global__ void matvec_w1(const float* __restrict__ W1, const float* __restrict__ a1s,
                          const float* __restrict__ a1d, float* __restrict__ w1s,
                          float* __restrict__ w1d) {
  int wid = (blockIdx.x * blockDim.x + threadIdx.x) >> 6;
  int lane = threadIdx.x & 63;
  if (wid >= IN_C) return;
  const float* row = W1 + (size_t)wid * HID;
  float s = 0.f, d = 0.f;
#pragma unroll
  for (int j0 = 0; j0 < HID; j0 += 64) {
    float w = row[j0 + lane];
    s += w * a1s[j0 + lane];
    d += w * a1d[j0 + lane];
  }
  s = wave_sum(s); d = wave_sum(d);
  if (lane == 0) { w1s[wid] = s; w1d[wid] = d; }
}

// alpha_s[i] = x[i].w1s ; alpha_d[i] = x[i].w1d  (one wave per node, float2)
__global__ void node_scores128(const float* __restrict__ x, const float* __restrict__ ws,
                               const float* __restrict__ wd, float* __restrict__ as_,
                               float* __restrict__ ad_) {
  int wid = (blockIdx.x * blockDim.x + threadIdx.x) >> 6;
  int lane = threadIdx.x & 63;
  if (wid >= N_NODES) return;
  float2 v = ((const float2*)(x + (size_t)wid * IN_C))[lane];
  float2 w1 = ((const float2*)ws)[lane];
  float2 w2 = ((const float2*)wd)[lane];
  float s = wave_sum(v.x * w1.x + v.y * w1.y);
  float d = wave_sum(v.x * w2.x + v.y * w2.y);
  if (lane == 0) { as_[wid] = s; ad_[wid] = d; }
}

// ---- fused segment-softmax + aggregation, layer 1 (128 ch, input space) ----
__global__ void sm_agg1(const int* __restrict__ row_ptr, const int* __restrict__ csr_src,
                        const float* __restrict__ as_, const float* __restrict__ ad_,
                        const float* __restrict__ x, float* __restrict__ xa) {
  int wid = (blockIdx.x * blockDim.x + threadIdx.x) >> 6;
  int lane = threadIdx.x & 63;
  if (wid >= N_NODES) return;
  int beg = row_ptr[wid], end = row_ptr[wid + 1];
  int deg = end - beg;
  float adv = ad_[wid];
  float2 acc = make_float2(0.f, 0.f);
  if (deg <= 64) {
    int s = 0; float sc = -3.4e38f;
    if (lane < deg) { s = csr_src[beg + lane]; sc = leaky(as_[s] + adv); }
    float m = wave_max(sc);
    float ex = (lane < deg) ? __expf(sc - m) : 0.f;
    float sum = wave_sum(ex);
    float a = ex / sum;
    for (int kk = 0; kk < deg; kk++) {
      float w = __shfl(a, kk, 64);
      int sv = __shfl(s, kk, 64);
      float2 r = ((const float2*)(x + (size_t)sv * IN_C))[lane];
      acc.x += w * r.x; acc.y += w * r.y;
    }
  } else {  // fallback (never for this graph size, kept for correctness)
    float m = -3.4e38f;
    for (int k = beg + lane; k < end; k += 64)
      m = fmaxf(m, leaky(as_[csr_src[k]] + adv));
    m = wave_max(m);
    float sum = 0.f;
    for (int k = beg + lane; k < end; k += 64)
      sum += __expf(leaky(as_[csr_src[k]] + adv) - m);
    sum = wave_sum(sum);
    float inv = 1.f / sum;
    for (int k = beg; k < end; k++) {
      int sv = csr_src[k];
      float w = __expf(leaky(as_[sv] + adv) - m) * inv;
      float2 r = ((const float2*)(x + (size_t)sv * IN_C))[lane];
      acc.x += w * r.x; acc.y += w * r.y;
    }
  }
  ((float2*)(xa + (size_t)wid * IN_C))[lane] = acc;
}

// ---- fused gemm1(relu) + gemm2 + layer-2 node scores ----------------------
// h2 = relu(xa@W1+b1)@W2 ; as2 = h2@a2s ; ad2 = h2@a2d
__launch_bounds__(256)
__global__ void fused_gemm(const float* __restrict__ xa, const float* __restrict__ W1,
                           const float* __restrict__ b1, const float* __restrict__ W2,
                           const float* __restrict__ a2s, const float* __restrict__ a2d,
                           float* __restrict__ h2, float* __restrict__ as2,
                           float* __restrict__ ad2) {
  __shared__ float xsT[IN_C][65];   // A tile transposed: [k][row], 33.3 KB
  __shared__ float ts[64][68];      // out1 slab: [row][col within jt], 17.4 KB
  int m0 = blockIdx.x * 64;
  int t = threadIdx.x;
  int tr = t >> 4, tc = t & 15;

  // stage A tile (transposed)
#pragma unroll
  for (int j = 0; j < 8; j++) {
    int idx = t + j * 256;          // 2048 float4 slots
    int row = idx >> 5, c4 = idx & 31;
    int gr = m0 + row;
    float4 v = make_float4(0.f, 0.f, 0.f, 0.f);
    if (gr < N_NODES) v = *(const float4*)(xa + (size_t)gr * IN_C + c4 * 4);
    xsT[c4 * 4 + 0][row] = v.x;
    xsT[c4 * 4 + 1][row] = v.y;
    xsT[c4 * 4 + 2][row] = v.z;
    xsT[c4 * 4 + 3][row] = v.w;
  }
  __syncthreads();

  float acc2[4][4] = {};
  for (int jt = 0; jt < 8; jt++) {
    int n0 = jt * 64;
    // --- gemm1 slab: tt = relu(xsT^T @ W1[:, n0:n0+64] + b1) ---
    float tt[4][4] = {};
    const float* wp = W1 + n0 + tc * 4;
#pragma unroll 8
    for (int k = 0; k < IN_C; k++) {
      float4 a = *(const float4*)&xsT[k][tr * 4];
      float4 b = *(const float4*)(wp + (size_t)k * HID);
      tt[0][0] += a.x * b.x; tt[0][1] += a.x * b.y; tt[0][2] += a.x * b.z; tt[0][3] += a.x * b.w;
      tt[1][0] += a.y * b.x; tt[1][1] += a.y * b.y; tt[1][2] += a.y * b.z; tt[1][3] += a.y * b.w;
      tt[2][0] += a.z * b.x; tt[2][1] += a.z * b.y; tt[2][2] += a.z * b.z; tt[2][3] += a.z * b.w;
      tt[3][0] += a.w * b.x; tt[3][1] += a.w * b.y; tt[3][2] += a.w * b.z; tt[3][3] += a.w * b.w;
    }
    float4 bias = *(const float4*)(b1 + n0 + tc * 4);
#pragma unroll
    for (int r = 0; r < 4; r++) {
      tt[r][0] = fmaxf(tt[r][0] + bias.x, 0.f);
      tt[r][1] = fmaxf(tt[r][1] + bias.y, 0.f);
      tt[r][2] = fmaxf(tt[r][2] + bias.z, 0.f);
      tt[r][3] = fmaxf(tt[r][3] + bias.w, 0.f);
    }
    __syncthreads();                 // previous jt's ts reads complete
#pragma unroll
    for (int r = 0; r < 4; r++)
      *(float4*)&ts[tr * 4 + r][tc * 4] = make_float4(tt[r][0], tt[r][1], tt[r][2], tt[r][3]);
    __syncthreads();
    // --- gemm2 partial: acc2 += ts @ W2[n0:n0+64, :] ---
    const float* w2p = W2 + (size_t)n0 * OUT2 + tc * 4;
#pragma unroll 8
    for (int j = 0; j < 64; j++) {
      float4 b = *(const float4*)(w2p + (size_t)j * OUT2);
      float a0 = ts[tr * 4 + 0][j], a1 = ts[tr * 4 + 1][j];
      float a2 = ts[tr * 4 + 2][j], a3 = ts[tr * 4 + 3][j];
      acc2[0][0] += a0 * b.x; acc2[0][1] += a0 * b.y; acc2[0][2] += a0 * b.z; acc2[0][3] += a0 * b.w;
      acc2[1][0] += a1 * b.x; acc2[1][1] += a1 * b.y; acc2[1][2] += a1 * b.z; acc2[1][3] += a1 * b.w;
      acc2[2][0] += a2 * b.x; acc2[2][1] += a2 * b.y; acc2[2][2] += a2 * b.z; acc2[2][3] += a2 * b.w;
      acc2[3][0] += a3 * b.x; acc2[3][1] += a3 * b.y; acc2[3][2] += a3 * b.z; acc2[3][3] += a3 * b.w;
    }
  }

  // epilogue: h2 write + fused layer-2 node scores
  float4 s4 = *(const float4*)(a2s + tc * 4);
  float4 d4 = *(const float4*)(a2d + tc * 4);
#pragma unroll
  for (int r = 0; r < 4; r++) {
    int gr = m0 + tr * 4 + r;
    if (gr < N_NODES)
      *(float4*)(h2 + (size_t)gr * OUT2 + tc * 4) =
          make_float4(acc2[r][0], acc2[r][1], acc2[r][2], acc2[r][3]);
    float sp = acc2[r][0] * s4.x + acc2[r][1] * s4.y + acc2[r][2] * s4.z + acc2[r][3] * s4.w;
    float dp = acc2[r][0] * d4.x + acc2[r][1] * d4.y + acc2[r][2] * d4.z + acc2[r][3] * d4.w;
#pragma unroll
    for (int o = 1; o < 16; o <<= 1) {
      sp += __shfl_xor(sp, o, 64);
      dp += __shfl_xor(dp, o, 64);
    }
    if (tc == 0 && gr < N_NODES) { as2[gr] = sp; ad2[gr] = dp; }
  }
}

// ---- fused layer-2 softmax + aggregation + relu + FC head ------------------
__global__ void sm_agg2_final(const int* __restrict__ row_ptr, const int* __restrict__ csr_src,
                              const float* __restrict__ as_, const float* __restrict__ ad_,
                              const float* __restrict__ h2, const float* __restrict__ b2,
                              const float* __restrict__ fcW, const float* __restrict__ fcb,
                              float* __restrict__ out) {
  int wid = (blockIdx.x * blockDim.x + threadIdx.x) >> 6;
  int lane = threadIdx.x & 63;
  if (wid >= N_NODES) return;
  int beg = row_ptr[wid], end = row_ptr[wid + 1];
  int deg = end - beg;
  float adv = ad_[wid];
  float acc = 0.f;
  if (deg <= 64) {
    int s = 0; float sc = -3.4e38f;
    if (lane < deg) { s = csr_src[beg + lane]; sc = leaky(as_[s] + adv); }
    float m = wave_max(sc);
    float ex = (lane < deg) ? __expf(sc - m) : 0.f;
    float sum = wave_sum(ex);
    float a = ex / sum;
    for (int kk = 0; kk < deg; kk++) {
      float w = __shfl(a, kk, 64);
      int sv = __shfl(s, kk, 64);
      acc += w * h2[(size_t)sv * OUT2 + lane];
    }
  } else {
    float m = -3.4e38f;
    for (int k = beg + lane; k < end; k += 64)
      m = fmaxf(m, leaky(as_[csr_src[k]] + adv));
    m = wave_max(m);
    float sum = 0.f;
    for (int k = beg + lane; k < end; k += 64)
      sum += __expf(leaky(as_[csr_src[k]] + adv) - m);
    sum = wave_sum(sum);
    float inv = 1.f / sum;
    for (int k = beg; k < end; k++) {
      int sv = csr_src[k];
      float w = __expf(leaky(as_[sv] + adv) - m) * inv;
      acc += w * h2[(size_t)sv * OUT2 + lane];
    }
  }
  float v = fmaxf(acc + b2[lane], 0.f);
  float2 fw = ((const float2*)fcW)[lane];
  float f0 = wave_sum(v * fw.x);
  float f1 = wave_sum(v * fw.y);
  if (lane == 0) {
    out[(size_t)wid * 2 + 0] = f0 + fcb[0];
    out[(size_t)wid * 2 + 1] = f1 + fcb[1];
  }
}

extern "C" void kernel_launch(void* const* d_in, const int* in_sizes, int n_in,
                              void* d_out, int out_size, void* d_ws, size_t ws_size,
                              hipStream_t stream) {
  const float* x    = (const float*)d_in[0];
  const int*   ei   = (const int*)d_in[1];
  const float* W1   = (const float*)d_in[2];
  const float* a1s  = (const float*)d_in[3];
  const float* a1d  = (const float*)d_in[4];
  const float* b1   = (const float*)d_in[5];
  const float* W2   = (const float*)d_in[6];
  const float* a2s  = (const float*)d_in[7];
  const float* a2d  = (const float*)d_in[8];
  const float* b2   = (const float*)d_in[9];
  const float* fcW  = (const float*)d_in[10];
  const float* fcb  = (const float*)d_in[11];
  float* out = (float*)d_out;

  char* p = (char*)d_ws;
  float* xa    = (float*)p; p += (size_t)N_NODES * IN_C * 4;
  float* h2    = (float*)p; p += (size_t)N_NODES * OUT2 * 4;
  float* as1   = (float*)p; p += (size_t)N_NODES * 4;   // reused for layer-2 scores
  float* ad1   = (float*)p; p += (size_t)N_NODES * 4;
  float* w1s   = (float*)p; p += 256 * 4;
  float* w1d   = (float*)p; p += 256 * 4;
  int* row_ptr = (int*)p;   p += (size_t)(N_NODES + 4) * 4;
  int* deg     = (int*)p;   p += (size_t)N_NODES * 4;   // also reused as cursor
  int* bsum    = (int*)p;   p += 64 * 4;
  int* boff    = (int*)p;   p += 64 * 4;
  int* csr_src = (int*)p;   p += (size_t)E_TOT * 4;

  const int edge_blocks = (E_TOT + 255) / 256;
  const int node_wave_blocks = (N_NODES + 3) / 4;   // 4 waves per 256-thread block
  const int m_tiles = (N_NODES + 63) / 64;
  const int scan_blocks = (N_NODES + 1023) / 1024;  // 49

  // ---- CSR build ----
  hipMemsetAsync(deg, 0, (size_t)N_NODES * 4, stream);
  count_deg<<<edge_blocks, 256, 0, stream>>>(ei, deg);
  scanA<<<scan_blocks, 1024, 0, stream>>>(deg, bsum);
  scanB<<<1, 64, 0, stream>>>(bsum, boff, scan_blocks);
  scanC<<<scan_blocks, 1024, 0, stream>>>(deg, boff, row_ptr);
  hipMemsetAsync(deg, 0, (size_t)N_NODES * 4, stream);
  fill_csr<<<edge_blocks, 256, 0, stream>>>(ei, row_ptr, deg, csr_src);

  // ---- layer 1: scores -> fused softmax+aggregate (input space) ----
  matvec_w1<<<(IN_C + 3) / 4, 256, 0, stream>>>(W1, a1s, a1d, w1s, w1d);
  node_scores128<<<node_wave_blocks, 256, 0, stream>>>(x, w1s, w1d, as1, ad1);
  sm_agg1<<<node_wave_blocks, 256, 0, stream>>>(row_ptr, csr_src, as1, ad1, x, xa);

  // ---- fused gemm1+relu+gemm2+layer-2 scores ----
  fused_gemm<<<m_tiles, 256, 0, stream>>>(xa, W1, b1, W2, a2s, a2d, h2, as1, ad1);

  // ---- layer 2: fused softmax+aggregate+relu+head ----
  sm_agg2_final<<<node_wave_blocks, 256, 0, stream>>>(row_ptr, csr_src, as1, ad1, h2, b2,
                                                      fcW, fcb, out);
}